// Round 1
// baseline (108.086 us; speedup 1.0000x reference)
//
#include <hip/hip_runtime.h>

#define B_    4
#define NPTS  8192          // N == M == 8192
#define NJ    16            // number of j-chunks per direction
#define JC    (NPTS / NJ)   // 512 dst points per chunk
#define PT    4             // src points per thread in pass1
#define BLK   256
#define ITILE (BLK * PT)    // 1024 src points per block

// ws layout (bytes):
//   gtT      float4[B*NPTS]      @ 0        (512 KiB)
//   predT    float4[B*NPTS]      @ 512K
//   partial1 float[B*NPTS*NJ]    @ 1M       (2 MiB)  pred->gt chunk mins
//   partial2 float[B*NPTS*NJ]    @ 3M       (2 MiB)  gt->pred chunk mins
//   acc      float[1]            @ 5M
#define OFF_GTT   0
#define OFF_PREDT (512u * 1024u)
#define OFF_P1    (1024u * 1024u)
#define OFF_P2    (3u * 1024u * 1024u)
#define OFF_ACC   (5u * 1024u * 1024u)

// Transform both clouds: (x,y,z) -> (-2x, -2y, -2z, x^2+y^2+z^2)
__global__ __launch_bounds__(256) void prep_kernel(
    const float* __restrict__ pred, const float* __restrict__ gt,
    float4* __restrict__ predT, float4* __restrict__ gtT, int total) {
  int i = blockIdx.x * blockDim.x + threadIdx.x;
  if (i >= total) return;
  float x = pred[3 * i + 0], y = pred[3 * i + 1], z = pred[3 * i + 2];
  predT[i] = make_float4(-2.f * x, -2.f * y, -2.f * z,
                         fmaf(x, x, fmaf(y, y, z * z)));
  x = gt[3 * i + 0]; y = gt[3 * i + 1]; z = gt[3 * i + 2];
  gtT[i] = make_float4(-2.f * x, -2.f * y, -2.f * z,
                       fmaf(x, x, fmaf(y, y, z * z)));
}

// For each src point i, compute min over one chunk of dst of (yy_j - 2 p_i.g_j).
// grid: (NPTS/ITILE, NJ, 2*B_)   z = dir*B_ + b
__global__ __launch_bounds__(BLK) void pass1_kernel(
    const float* __restrict__ pred, const float* __restrict__ gt,
    const float4* __restrict__ gtT, const float4* __restrict__ predT,
    float* __restrict__ partial1, float* __restrict__ partial2) {
  __shared__ float4 lds[JC];

  const int zb  = blockIdx.z;
  const int dir = zb >> 2;          // 0: pred->gt, 1: gt->pred
  const int b   = zb & 3;
  const float*  src     = dir ? gt     : pred;
  const float4* dstT    = dir ? predT  : gtT;
  float*        partial = dir ? partial2 : partial1;

  const int tid   = threadIdx.x;
  const int jbase = blockIdx.y * JC;
  const int ibase = blockIdx.x * ITILE;

  // Stage dst chunk into LDS (coalesced float4 loads)
  for (int k = tid; k < JC; k += BLK)
    lds[k] = dstT[b * NPTS + jbase + k];

  float px[PT], py[PT], pz[PT], m[PT];
#pragma unroll
  for (int p = 0; p < PT; ++p) {
    const int i = ibase + p * BLK + tid;
    const float* s = src + ((size_t)b * NPTS + i) * 3;
    px[p] = s[0]; py[p] = s[1]; pz[p] = s[2];
    m[p] = 1e30f;
  }
  __syncthreads();

#pragma unroll 4
  for (int jj = 0; jj < JC; ++jj) {
    const float4 g = lds[jj];   // broadcast read, conflict-free
#pragma unroll
    for (int p = 0; p < PT; ++p) {
      float t = fmaf(px[p], g.x, g.w);
      t = fmaf(py[p], g.y, t);
      t = fmaf(pz[p], g.z, t);
      m[p] = fminf(m[p], t);
    }
  }

#pragma unroll
  for (int p = 0; p < PT; ++p) {
    const int i = ibase + p * BLK + tid;
    partial[((size_t)b * NPTS + i) * NJ + blockIdx.y] = m[p];
  }
}

// Per point: min over NJ partials + xx_i; block-reduce; one atomic per block.
// grid: 2*B_*NPTS/256 blocks; first half dir0, second half dir1.
__global__ __launch_bounds__(256) void pass2_kernel(
    const float* __restrict__ pred, const float* __restrict__ gt,
    const float* __restrict__ partial1, const float* __restrict__ partial2,
    float* __restrict__ acc) {
  const int total = B_ * NPTS;
  const int gid = blockIdx.x * 256 + threadIdx.x;
  const int dir = gid >= total;          // blocks never straddle (total%256==0)
  const int idx = dir ? gid - total : gid;
  const float* src     = dir ? gt       : pred;
  const float* partial = dir ? partial2 : partial1;

  const float4* p4 = (const float4*)(partial + (size_t)idx * NJ);
  float m = 1e30f;
#pragma unroll
  for (int k = 0; k < NJ / 4; ++k) {
    const float4 v = p4[k];
    m = fminf(m, fminf(fminf(v.x, v.y), fminf(v.z, v.w)));
  }
  const float x = src[3 * idx + 0], y = src[3 * idx + 1], z = src[3 * idx + 2];
  const float dist = fmaf(x, x, fmaf(y, y, z * z)) + m;

  __shared__ float red[256];
  const int tid = threadIdx.x;
  red[tid] = dist;
  __syncthreads();
  for (int s = 128; s > 0; s >>= 1) {
    if (tid < s) red[tid] += red[tid + s];
    __syncthreads();
  }
  if (tid == 0) atomicAdd(acc, red[0] * (1.0f / (B_ * NPTS)));
}

__global__ void finalize_kernel(const float* __restrict__ acc,
                                float* __restrict__ out) {
  out[0] = acc[0];
}

extern "C" void kernel_launch(void* const* d_in, const int* in_sizes, int n_in,
                              void* d_out, int out_size, void* d_ws, size_t ws_size,
                              hipStream_t stream) {
  const float* pred = (const float*)d_in[0];
  const float* gt   = (const float*)d_in[1];
  char* ws = (char*)d_ws;
  float4* gtT      = (float4*)(ws + OFF_GTT);
  float4* predT    = (float4*)(ws + OFF_PREDT);
  float*  partial1 = (float*)(ws + OFF_P1);
  float*  partial2 = (float*)(ws + OFF_P2);
  float*  acc      = (float*)(ws + OFF_ACC);

  hipMemsetAsync(acc, 0, sizeof(float), stream);

  const int total = B_ * NPTS;
  prep_kernel<<<(total + 255) / 256, 256, 0, stream>>>(pred, gt, predT, gtT, total);

  dim3 g1(NPTS / ITILE, NJ, 2 * B_);
  pass1_kernel<<<g1, BLK, 0, stream>>>(pred, gt, gtT, predT, partial1, partial2);

  pass2_kernel<<<(2 * total) / 256, 256, 0, stream>>>(pred, gt, partial1, partial2, acc);

  finalize_kernel<<<1, 1, 0, stream>>>(acc, (float*)d_out);
}

// Round 2
// 101.651 us; speedup vs baseline: 1.0633x; 1.0633x over previous
//
#include <hip/hip_runtime.h>

typedef float f32x2 __attribute__((ext_vector_type(2)));

#define B_    4
#define NPTS  8192          // N == M == 8192
#define NJ    16            // j-chunks per direction
#define JC    (NPTS / NJ)   // 512 dst points per chunk
#define JP    (JC / 2)      // 256 dst pairs per chunk
#define PT    8             // src points per thread
#define BLK   256
#define ITILE (BLK * PT)    // 2048 src points per block
#define TOT   (B_ * NPTS)   // 32768

// ws layout: partial float[2 * B_ * NJ * NPTS] = 4 MiB @ offset 0
// layout index: ((dir*B_ + b)*NJ + jchunk)*NPTS + i   (coalesced write AND read)

// Fused transform+stage+min kernel.
// grid: (NPTS/ITILE, NJ, 2*B_), z = dir*4 + b
__global__ __launch_bounds__(BLK) void pass1_kernel(
    const float* __restrict__ pred, const float* __restrict__ gt,
    float* __restrict__ partial) {
  // dst chunk, transformed and pre-paired:
  // lds[jp][0] = (-2x0, -2x1, -2y0, -2y1), lds[jp][1] = (-2z0, -2z1, w0, w1)
  __shared__ float4 lds[JP][2];

  const int zb  = blockIdx.z;
  const int dir = zb >> 2;          // 0: pred->gt, 1: gt->pred
  const int b   = zb & 3;
  const float* src = dir ? gt   : pred;
  const float* dst = dir ? pred : gt;

  const int tid   = threadIdx.x;
  const int jbase = blockIdx.y * JC;
  const int ibase = blockIdx.x * ITILE;

  // Stage + transform one dst pair per thread (JP == BLK).
  {
    const float* g = dst + ((size_t)b * NPTS + jbase + 2 * tid) * 3;
    const float x0 = g[0], y0 = g[1], z0 = g[2];
    const float x1 = g[3], y1 = g[4], z1 = g[5];
    lds[tid][0] = make_float4(-2.f * x0, -2.f * x1, -2.f * y0, -2.f * y1);
    lds[tid][1] = make_float4(-2.f * z0, -2.f * z1,
                              fmaf(x0, x0, fmaf(y0, y0, z0 * z0)),
                              fmaf(x1, x1, fmaf(y1, y1, z1 * z1)));
  }

  // Load PT src points; keep splatted f32x2 copies (loop-invariant, hoisted).
  f32x2 px[PT], py[PT], pz[PT];
  float m[PT];
#pragma unroll
  for (int p = 0; p < PT; ++p) {
    const int i = ibase + p * BLK + tid;
    const float* s = src + ((size_t)b * NPTS + i) * 3;
    px[p] = (f32x2){s[0], s[0]};
    py[p] = (f32x2){s[1], s[1]};
    pz[p] = (f32x2){s[2], s[2]};
    m[p] = 1e30f;
  }
  __syncthreads();

#pragma unroll 2
  for (int jp = 0; jp < JP; ++jp) {
    const float4 c0 = lds[jp][0];   // x0 x1 y0 y1 (uniform -> broadcast read)
    const float4 c1 = lds[jp][1];   // z0 z1 w0 w1
    const f32x2 gx = {c0.x, c0.y};
    const f32x2 gy = {c0.z, c0.w};
    const f32x2 gz = {c1.x, c1.y};
    const f32x2 gw = {c1.z, c1.w};
#pragma unroll
    for (int p = 0; p < PT; ++p) {
      f32x2 t = __builtin_elementwise_fma(px[p], gx, gw);   // v_pk_fma_f32
      t = __builtin_elementwise_fma(py[p], gy, t);
      t = __builtin_elementwise_fma(pz[p], gz, t);
      m[p] = fminf(fminf(t.x, t.y), m[p]);                  // v_min3_f32
    }
  }

#pragma unroll
  for (int p = 0; p < PT; ++p) {
    const int i = ibase + p * BLK + tid;
    partial[((size_t)(dir * B_ + b) * NJ + blockIdx.y) * NPTS + i] = m[p];
  }
}

// Per point: min over NJ chunk-partials (coalesced), add ||x||^2,
// block-reduce, one scaled atomic per block into d_out.
__global__ __launch_bounds__(256) void pass2_kernel(
    const float* __restrict__ pred, const float* __restrict__ gt,
    const float* __restrict__ partial, float* __restrict__ out) {
  const int gid = blockIdx.x * 256 + threadIdx.x;
  const int dir = gid >= TOT;         // blocks never straddle (TOT % 256 == 0)
  const int idx = dir ? gid - TOT : gid;   // = b*NPTS + i
  const float* src = dir ? gt : pred;
  const int b = idx >> 13;            // NPTS == 8192
  const int i = idx & (NPTS - 1);

  const float* p = partial + ((size_t)(dir * B_ + b) * NJ) * NPTS + i;
  float m = 1e30f;
#pragma unroll
  for (int k = 0; k < NJ; ++k) m = fminf(m, p[(size_t)k * NPTS]);

  const float x = src[3 * idx + 0], y = src[3 * idx + 1], z = src[3 * idx + 2];
  const float dist = fmaf(x, x, fmaf(y, y, z * z)) + m;

  __shared__ float red[256];
  const int tid = threadIdx.x;
  red[tid] = dist;
  __syncthreads();
  for (int s = 128; s > 0; s >>= 1) {
    if (tid < s) red[tid] += red[tid + s];
    __syncthreads();
  }
  if (tid == 0) atomicAdd(out, red[0] * (1.0f / TOT));
}

extern "C" void kernel_launch(void* const* d_in, const int* in_sizes, int n_in,
                              void* d_out, int out_size, void* d_ws, size_t ws_size,
                              hipStream_t stream) {
  const float* pred = (const float*)d_in[0];
  const float* gt   = (const float*)d_in[1];
  float* partial = (float*)d_ws;
  float* out = (float*)d_out;

  hipMemsetAsync(out, 0, out_size * sizeof(float), stream);

  dim3 g1(NPTS / ITILE, NJ, 2 * B_);   // (4, 16, 8) = 512 blocks
  pass1_kernel<<<g1, BLK, 0, stream>>>(pred, gt, partial);

  pass2_kernel<<<(2 * TOT) / 256, 256, 0, stream>>>(pred, gt, partial, out);
}